// Round 6
// baseline (416.962 us; speedup 1.0000x reference)
//
#include <hip/hip_runtime.h>
#include <cmath>

// Problem constants: B=2, H=16, S=2048, D=1024, dh=64
#define SEQ 2048
#define NH  16

using bf16x8 = __attribute__((ext_vector_type(8))) short;
using f32x4  = __attribute__((ext_vector_type(4))) float;
using u16x8  = __attribute__((ext_vector_type(8))) unsigned short;
using u16x4  = __attribute__((ext_vector_type(4))) unsigned short;

#define MFMA __builtin_amdgcn_mfma_f32_16x16x32_bf16

static __device__ __forceinline__ unsigned short f2b(float f) {
  unsigned int x = __float_as_uint(f);
  x += 0x7fffu + ((x >> 16) & 1u);
  return (unsigned short)(x >> 16);
}

static __device__ __forceinline__ u16x8 cvt8(f32x4 a, f32x4 b) {
  u16x8 o;
  o[0] = f2b(a[0]); o[1] = f2b(a[1]); o[2] = f2b(a[2]); o[3] = f2b(a[3]);
  o[4] = f2b(b[0]); o[5] = f2b(b[1]); o[6] = f2b(b[2]); o[7] = f2b(b[3]);
  return o;
}

// ---------------------------------------------------------------------------
// Kernel 0: one-shot f32 -> bf16 convert of x and [Wq;Wk;Wv] into workspace.
// ---------------------------------------------------------------------------
__global__ __launch_bounds__(256) void convert_kernel(
    const float* __restrict__ x, const float* __restrict__ wq,
    const float* __restrict__ wk, const float* __restrict__ wv,
    unsigned short* __restrict__ dst) {
  int bid = blockIdx.x;
  const float* src;
  size_t off;
  if (bid < 2048)      { src = x;  off = (size_t)bid * 2048; }
  else if (bid < 2560) { src = wq; off = (size_t)(bid - 2048) * 2048; dst += 4194304; }
  else if (bid < 3072) { src = wk; off = (size_t)(bid - 2560) * 2048; dst += 4194304 + 1048576; }
  else                 { src = wv; off = (size_t)(bid - 3072) * 2048; dst += 4194304 + 2097152; }
  size_t i = off + (size_t)threadIdx.x * 8;
  f32x4 a = *(const f32x4*)(src + i);
  f32x4 b = *(const f32x4*)(src + i + 4);
  *(u16x8*)(dst + i) = cvt8(a, b);
}

// ---------------------------------------------------------------------------
// Kernel 1: m97-structure bf16 GEMM, 128x128 tile, BK=32, 4 waves (2x2),
// global_load_lds width-16 staging, source-swizzled LDS. (unchanged)
// ---------------------------------------------------------------------------
template <int VAR>
__global__ __launch_bounds__(256) void gemm_qkv(
    const unsigned short* __restrict__ x_bf,   // [4096][1024]
    const unsigned short* __restrict__ w_bf,   // [3072][1024] = [wq;wk;wv]
    const float* __restrict__ bq, const float* __restrict__ bk,
    const float* __restrict__ bv,
    unsigned short* __restrict__ q_ws, unsigned short* __restrict__ k_ws,
    unsigned short* __restrict__ vt_ws) {
  const int st  = blockIdx.x;
  const int et  = blockIdx.y;
  const int tid = threadIdx.x;
  const int w = tid >> 6, l = tid & 63, c = l & 15, g = l >> 4;
  const int wr = w >> 1, wc = w & 1;

  __shared__ unsigned short Xt[128 * 32];
  __shared__ unsigned short Wt[128 * 32];

  const int wrow_base = (VAR == 0 ? et * 128 : 2048 + et * 128);

  f32x4 acc[4][4];
#pragma unroll
  for (int m = 0; m < 4; ++m)
#pragma unroll
    for (int n = 0; n < 4; ++n) acc[m][n] = f32x4{0.f, 0.f, 0.f, 0.f};

  for (int kb = 0; kb < 32; ++kb) {
    __syncthreads();
#pragma unroll
    for (int i = 0; i < 2; ++i) {
      int row   = i * 64 + w * 16 + (l >> 2);
      int chunk = (l & 3) ^ ((row >> 1) & 3);
      const unsigned short* gx = x_bf + (size_t)(st * 128 + row) * 1024 + kb * 32 + chunk * 8;
      const unsigned short* gw = w_bf + (size_t)(wrow_base + row) * 1024 + kb * 32 + chunk * 8;
      __builtin_amdgcn_global_load_lds(
          (const __attribute__((address_space(1))) void*)gx,
          (__attribute__((address_space(3))) void*)&Xt[(i * 64 + w * 16) * 32], 16, 0, 0);
      __builtin_amdgcn_global_load_lds(
          (const __attribute__((address_space(1))) void*)gw,
          (__attribute__((address_space(3))) void*)&Wt[(i * 64 + w * 16) * 32], 16, 0, 0);
    }
    asm volatile("s_waitcnt vmcnt(0)" ::: "memory");
    __syncthreads();

    bf16x8 af[4], bfr[4];
#pragma unroll
    for (int m = 0; m < 4; ++m) {
      int ar = wr * 64 + m * 16 + c;
      int br = wc * 64 + m * 16 + c;
      int ach = g ^ ((ar >> 1) & 3);
      int bch = g ^ ((br >> 1) & 3);
      if (VAR == 0) {
        af[m]  = *(const bf16x8*)(&Wt[ar * 32 + ach * 8]);
        bfr[m] = *(const bf16x8*)(&Xt[br * 32 + bch * 8]);
      } else {
        af[m]  = *(const bf16x8*)(&Xt[ar * 32 + ach * 8]);
        bfr[m] = *(const bf16x8*)(&Wt[br * 32 + bch * 8]);
      }
    }
#pragma unroll
    for (int m = 0; m < 4; ++m)
#pragma unroll
      for (int n = 0; n < 4; ++n)
        acc[m][n] = MFMA(af[m], bfr[n], acc[m][n], 0, 0, 0);
  }

  const float QSC = 0.125f * 1.44269504088896340736f; // 1/sqrt(64) * log2(e)
  if (VAR == 0) {
    const bool isq = (et < 8);
#pragma unroll
    for (int m = 0; m < 4; ++m) {
      int e0 = et * 128 + wr * 64 + m * 16 + g * 4;
      int eh = e0 & 1023;
      int h = eh >> 6, d0 = eh & 63;
#pragma unroll
      for (int n = 0; n < 4; ++n) {
        int s = st * 128 + wc * 64 + n * 16 + c;
        int b = s >> 11, sl = s & 2047;
        u16x4 p;
        if (isq) {
#pragma unroll
          for (int r = 0; r < 4; ++r) p[r] = f2b((acc[m][n][r] + bq[eh + r]) * QSC);
          *(u16x4*)(&q_ws[((size_t)(b * NH + h) * SEQ + sl) * 64 + d0]) = p;
        } else {
#pragma unroll
          for (int r = 0; r < 4; ++r) p[r] = f2b(acc[m][n][r] + bk[eh + r]);
          *(u16x4*)(&k_ws[((size_t)(b * NH + h) * SEQ + sl) * 64 + d0]) = p;
        }
      }
    }
  } else {
#pragma unroll
    for (int m = 0; m < 4; ++m) {
      int s0 = st * 128 + wr * 64 + m * 16 + g * 4;
      int b = s0 >> 11, sl0 = s0 & 2047;
#pragma unroll
      for (int n = 0; n < 4; ++n) {
        int e = et * 128 + wc * 64 + n * 16 + c;
        int h = e >> 6, d = e & 63;
        float bias = bv[e];
        u16x4 p;
#pragma unroll
        for (int r = 0; r < 4; ++r) p[r] = f2b(acc[m][n][r] + bias);
        *(u16x4*)(&vt_ws[((size_t)(b * NH + h) * 64 + d) * SEQ + sl0]) = p;
      }
    }
  }
}

// ---------------------------------------------------------------------------
// Kernel 2: rowsum — invl[bh][q] = 1 / sum_k exp2(q.k). Pure QK^T sweep,
// direct L2 reads (XCD-swizzled so K is L2-resident), no LDS, no barriers,
// unroll-4 for deep load pipelining. Also warms L2 for the attn kernel.
// ---------------------------------------------------------------------------
__global__ __launch_bounds__(256) void rowsum_kernel(
    const unsigned short* __restrict__ q_ws, const unsigned short* __restrict__ k_ws,
    float* __restrict__ invl_ws) {
  const int wg = blockIdx.x;
  const int xcd = wg & 7, idx = wg >> 3;
  const int bh = xcd * 4 + (idx & 3), qt = idx >> 2;  // XCD owns 4 bh
  const int tid = threadIdx.x;
  const int w = tid >> 6, l = tid & 63, c = l & 15, g = l >> 4;

  const unsigned short* qp = q_ws + ((size_t)bh * SEQ + qt * 64 + w * 16 + c) * 64 + g * 8;
  bf16x8 qf0 = *(const bf16x8*)(qp);
  bf16x8 qf1 = *(const bf16x8*)(qp + 32);
  const unsigned short* kbase = k_ws + (size_t)bh * SEQ * 64;

  float lsum = 0.f;
#pragma unroll 4
  for (int kt = 0; kt < 32; ++kt) {
    const unsigned short* kp = kbase + ((size_t)kt * 64 + c) * 64 + g * 8;
    f32x4 sa[4];
#pragma unroll
    for (int s = 0; s < 4; ++s) {
      bf16x8 k0 = *(const bf16x8*)(kp + s * 1024);
      bf16x8 k1 = *(const bf16x8*)(kp + s * 1024 + 32);
      sa[s] = f32x4{0.f, 0.f, 0.f, 0.f};
      sa[s] = MFMA(k0, qf0, sa[s], 0, 0, 0);
      sa[s] = MFMA(k1, qf1, sa[s], 0, 0, 0);
    }
#pragma unroll
    for (int s = 0; s < 4; ++s)
#pragma unroll
      for (int r = 0; r < 4; ++r) lsum += exp2f(sa[s][r]);
  }
  lsum += __shfl_xor(lsum, 16);
  lsum += __shfl_xor(lsum, 32);
  if (g == 0) invl_ws[(size_t)bh * SEQ + qt * 64 + w * 16 + c] = 1.f / lsum;
}

// ---------------------------------------------------------------------------
// Kernel 3: attention main — single pass, proven 2-phase staged template.
// Block = 4 waves x 64 q-rows. Per K-tile: global_load_lds stages K(8KB) +
// V^T(8KB) into double-buffered XOR-swizzled LDS (pre-swizzled global src);
// QK^T (swapped, A=K B=Q) -> exp2 -> probs(normalized, from f32 regs, NT
// f32x4) -> bf16 P via per-wave swizzled scratch -> PV. Counted vmcnt(4)
// leaves the 4 NT stores in flight; raw s_barrier; sched_barrier(0) pins
// issue order. LDS 40KB -> 4 blocks/CU = 16 waves/CU. XCD-swizzled grid.
// ---------------------------------------------------------------------------
__global__ __launch_bounds__(256, 4) void attn_kernel(
    const unsigned short* __restrict__ q_ws, const unsigned short* __restrict__ k_ws,
    const unsigned short* __restrict__ vt_ws, const float* __restrict__ invl_ws,
    float* __restrict__ out) {
  const int wg = blockIdx.x;
  const int xcd = wg & 7, idx = wg >> 3;
  const int bh = xcd * 4 + (idx & 3), qt = idx >> 2;  // XCD owns 4 bh
  const int tid = threadIdx.x;
  const int w = tid >> 6, l = tid & 63, c = l & 15, g = l >> 4;

  __shared__ unsigned short Kb[2][64 * 64];  // [k-row][d], swizzled, dbuf
  __shared__ unsigned short Vb[2][64 * 64];  // [d-row][k], swizzled, dbuf
  __shared__ unsigned short Ps[4][1024];     // per-wave P scratch, swizzled

  const unsigned short* qp = q_ws + ((size_t)bh * SEQ + qt * 64 + w * 16 + c) * 64 + g * 8;
  bf16x8 qf0 = *(const bf16x8*)(qp);
  bf16x8 qf1 = *(const bf16x8*)(qp + 32);
  const float inv = invl_ws[(size_t)bh * SEQ + qt * 64 + w * 16 + c];

  const unsigned short* kbase = k_ws + (size_t)bh * SEQ * 64;   // row stride 64
  const unsigned short* vbase = vt_ws + (size_t)bh * 64 * SEQ;  // row stride SEQ

  // staging geometry: wave w stages rows [w*16, w*16+16) of each 64x64 tile,
  // 2 x global_load_lds(16B) per tile per wave; source col pre-swizzled so
  // linear LDS holds byte-swizzled layout: LDS(r,b) = G(r, b ^ ((r&7)<<4)).
  const int srow = l >> 3;                       // 0..7
  const int scol = ((l & 7) ^ srow) << 3;        // u16 units (16B granule)

#define STAGE(BUF, KT)                                                         \
  {                                                                            \
    const unsigned short* ks_ = kbase + ((size_t)(KT) * 64 + w * 16) * 64;     \
    const unsigned short* vs_ = vbase + (size_t)(w * 16) * SEQ + (KT) * 64;    \
    __builtin_amdgcn_global_load_lds(                                          \
        (const __attribute__((address_space(1))) void*)(ks_ + (size_t)srow * 64 + scol), \
        (__attribute__((address_space(3))) void*)&Kb[BUF][(w * 16) * 64], 16, 0, 0);     \
    __builtin_amdgcn_global_load_lds(                                          \
        (const __attribute__((address_space(1))) void*)(ks_ + (size_t)(8 + srow) * 64 + scol), \
        (__attribute__((address_space(3))) void*)&Kb[BUF][(w * 16 + 8) * 64], 16, 0, 0); \
    __builtin_amdgcn_global_load_lds(                                          \
        (const __attribute__((address_space(1))) void*)(vs_ + (size_t)srow * SEQ + scol), \
        (__attribute__((address_space(3))) void*)&Vb[BUF][(w * 16) * 64], 16, 0, 0);     \
    __builtin_amdgcn_global_load_lds(                                          \
        (const __attribute__((address_space(1))) void*)(vs_ + (size_t)(8 + srow) * SEQ + scol), \
        (__attribute__((address_space(3))) void*)&Vb[BUF][(w * 16 + 8) * 64], 16, 0, 0); \
  }

  f32x4 ctx[4];
#pragma unroll
  for (int f = 0; f < 4; ++f) ctx[f] = f32x4{0.f, 0.f, 0.f, 0.f};

  float* prbase = out + (size_t)2 * SEQ * 1024 +
                  ((size_t)bh * SEQ + qt * 64 + w * 16 + c) * SEQ;

  const int sw   = (c & 7) << 4;   // byte swz for tile rows (R&7 == c&7)
  const int pswz = (c & 7) << 3;   // u16 swz for Ps

  // prologue
  STAGE(0, 0);
  asm volatile("s_waitcnt vmcnt(0)" ::: "memory");
  __builtin_amdgcn_s_barrier();
  __builtin_amdgcn_sched_barrier(0);

  for (int kt = 0; kt < 32; ++kt) {
    const int buf = kt & 1;
    if (kt < 31) STAGE(buf ^ 1, kt + 1);
    __builtin_amdgcn_sched_barrier(0);

    // ---- QK^T: A = K rows (s*16+c), B = Q
    f32x4 sa[4];
#pragma unroll
    for (int s = 0; s < 4; ++s) {
      const unsigned short* kb = &Kb[buf][(s * 16 + c) * 64];
      bf16x8 k0 = *(const bf16x8*)(kb + (((g * 16) ^ sw) >> 1));
      bf16x8 k1 = *(const bf16x8*)(kb + (((64 + g * 16) ^ sw) >> 1));
      sa[s] = f32x4{0.f, 0.f, 0.f, 0.f};
      sa[s] = MFMA(k0, qf0, sa[s], 0, 0, 0);
      sa[s] = MFMA(k1, qf1, sa[s], 0, 0, 0);
    }

    // ---- exp2 -> probs (normalized, f32 regs, NT) + unnorm bf16 -> Ps
#pragma unroll
    for (int s = 0; s < 4; ++s) {
      f32x4 pw;
      u16x4 pb;
#pragma unroll
      for (int r = 0; r < 4; ++r) {
        float p = exp2f(sa[s][r]);
        pw[r] = p * inv;
        pb[r] = f2b(p);
      }
      __builtin_nontemporal_store(pw, (f32x4*)(prbase + kt * 64 + s * 16 + g * 4));
      *(u16x4*)(&Ps[w][c * 64 + ((s * 16 + g * 4) ^ pswz)]) = pb;
    }

    // ---- PV: A = P (from same-wave scratch), B = V^T
#pragma unroll
    for (int W = 0; W < 2; ++W) {
      bf16x8 pa = *(const bf16x8*)(&Ps[w][c * 64 + ((W * 32 + g * 8) ^ pswz)]);
#pragma unroll
      for (int f = 0; f < 4; ++f) {
        const unsigned short* vb = &Vb[buf][(f * 16 + c) * 64];
        bf16x8 vbf = *(const bf16x8*)(vb + (((W * 64 + g * 16) ^ sw) >> 1));
        ctx[f] = MFMA(pa, vbf, ctx[f], 0, 0, 0);
      }
    }

    __builtin_amdgcn_sched_barrier(0);
    asm volatile("s_waitcnt vmcnt(4)" ::: "memory");  // 4 staging loads done; NT stores in flight
    __builtin_amdgcn_s_barrier();
    __builtin_amdgcn_sched_barrier(0);
  }
#undef STAGE

  // ---- ctx epilogue: lane holds C[q = g*4+r][d = f*16+c]
  const int b = bh >> 4, h = bh & 15;
  float invq[4];
#pragma unroll
  for (int r = 0; r < 4; ++r) invq[r] = __shfl(inv, g * 4 + r);
#pragma unroll
  for (int f = 0; f < 4; ++f)
#pragma unroll
    for (int r = 0; r < 4; ++r) {
      int s = qt * 64 + w * 16 + g * 4 + r;
      out[((size_t)b * SEQ + s) * 1024 + h * 64 + f * 16 + c] = ctx[f][r] * invq[r];
    }
}

extern "C" void kernel_launch(void* const* d_in, const int* in_sizes, int n_in,
                              void* d_out, int out_size, void* d_ws, size_t ws_size,
                              hipStream_t stream) {
  (void)in_sizes; (void)n_in; (void)out_size; (void)ws_size;
  const float* x  = (const float*)d_in[0];
  const float* wq = (const float*)d_in[1];
  const float* bq = (const float*)d_in[2];
  const float* wk = (const float*)d_in[3];
  const float* bk = (const float*)d_in[4];
  const float* wv = (const float*)d_in[5];
  const float* bv = (const float*)d_in[6];

  unsigned short* xw_bf = (unsigned short*)d_ws;            // x_bf + w_bf
  unsigned short* x_bf  = xw_bf;
  unsigned short* w_bf  = xw_bf + 4194304;
  unsigned short* q_ws  = xw_bf + 7340032;                  // [32][2048][64]
  unsigned short* k_ws  = q_ws + 4194304;                   // [32][2048][64]
  unsigned short* vt_ws = k_ws + 4194304;                   // [32][64][2048]
  float* invl_ws = (float*)(xw_bf + 19922944);              // [32][2048]
  float* out = (float*)d_out;

  convert_kernel<<<3584, 256, 0, stream>>>(x, wq, wk, wv, xw_bf);
  gemm_qkv<0><<<dim3(32, 16), 256, 0, stream>>>(x_bf, w_bf, bq, bk, bv, q_ws, k_ws, vt_ws);
  gemm_qkv<1><<<dim3(32, 8), 256, 0, stream>>>(x_bf, w_bf, bq, bk, bv, q_ws, k_ws, vt_ws);
  rowsum_kernel<<<1024, 256, 0, stream>>>(q_ws, k_ws, invl_ws);
  attn_kernel<<<1024, 256, 0, stream>>>(q_ws, k_ws, vt_ws, invl_ws, out);
}

// Round 7
// 336.088 us; speedup vs baseline: 1.2406x; 1.2406x over previous
//
#include <hip/hip_runtime.h>
#include <cmath>

// Problem constants: B=2, H=16, S=2048, D=1024, dh=64
#define SEQ 2048
#define NH  16

using bf16x8 = __attribute__((ext_vector_type(8))) short;
using f32x4  = __attribute__((ext_vector_type(4))) float;
using u16x8  = __attribute__((ext_vector_type(8))) unsigned short;
using u16x4  = __attribute__((ext_vector_type(4))) unsigned short;

#define MFMA __builtin_amdgcn_mfma_f32_16x16x32_bf16

static __device__ __forceinline__ unsigned short f2b(float f) {
  unsigned int x = __float_as_uint(f);
  x += 0x7fffu + ((x >> 16) & 1u);
  return (unsigned short)(x >> 16);
}

static __device__ __forceinline__ u16x8 cvt8(f32x4 a, f32x4 b) {
  u16x8 o;
  o[0] = f2b(a[0]); o[1] = f2b(a[1]); o[2] = f2b(a[2]); o[3] = f2b(a[3]);
  o[4] = f2b(b[0]); o[5] = f2b(b[1]); o[6] = f2b(b[2]); o[7] = f2b(b[3]);
  return o;
}

// ---------------------------------------------------------------------------
// Kernel 0: one-shot f32 -> bf16 convert of x and [Wq;Wk;Wv] into workspace.
// ---------------------------------------------------------------------------
__global__ __launch_bounds__(256) void convert_kernel(
    const float* __restrict__ x, const float* __restrict__ wq,
    const float* __restrict__ wk, const float* __restrict__ wv,
    unsigned short* __restrict__ dst) {
  int bid = blockIdx.x;
  const float* src;
  size_t off;
  if (bid < 2048)      { src = x;  off = (size_t)bid * 2048; }
  else if (bid < 2560) { src = wq; off = (size_t)(bid - 2048) * 2048; dst += 4194304; }
  else if (bid < 3072) { src = wk; off = (size_t)(bid - 2560) * 2048; dst += 4194304 + 1048576; }
  else                 { src = wv; off = (size_t)(bid - 3072) * 2048; dst += 4194304 + 2097152; }
  size_t i = off + (size_t)threadIdx.x * 8;
  f32x4 a = *(const f32x4*)(src + i);
  f32x4 b = *(const f32x4*)(src + i + 4);
  *(u16x8*)(dst + i) = cvt8(a, b);
}

// ---------------------------------------------------------------------------
// Kernel 1: m97-structure bf16 GEMM, 128x128 tile, BK=32, 4 waves (2x2),
// global_load_lds width-16 staging, source-swizzled LDS. (unchanged)
// ---------------------------------------------------------------------------
template <int VAR>
__global__ __launch_bounds__(256) void gemm_qkv(
    const unsigned short* __restrict__ x_bf,   // [4096][1024]
    const unsigned short* __restrict__ w_bf,   // [3072][1024] = [wq;wk;wv]
    const float* __restrict__ bq, const float* __restrict__ bk,
    const float* __restrict__ bv,
    unsigned short* __restrict__ q_ws, unsigned short* __restrict__ k_ws,
    unsigned short* __restrict__ vt_ws) {
  const int st  = blockIdx.x;
  const int et  = blockIdx.y;
  const int tid = threadIdx.x;
  const int w = tid >> 6, l = tid & 63, c = l & 15, g = l >> 4;
  const int wr = w >> 1, wc = w & 1;

  __shared__ unsigned short Xt[128 * 32];
  __shared__ unsigned short Wt[128 * 32];

  const int wrow_base = (VAR == 0 ? et * 128 : 2048 + et * 128);

  f32x4 acc[4][4];
#pragma unroll
  for (int m = 0; m < 4; ++m)
#pragma unroll
    for (int n = 0; n < 4; ++n) acc[m][n] = f32x4{0.f, 0.f, 0.f, 0.f};

  for (int kb = 0; kb < 32; ++kb) {
    __syncthreads();
#pragma unroll
    for (int i = 0; i < 2; ++i) {
      int row   = i * 64 + w * 16 + (l >> 2);
      int chunk = (l & 3) ^ ((row >> 1) & 3);
      const unsigned short* gx = x_bf + (size_t)(st * 128 + row) * 1024 + kb * 32 + chunk * 8;
      const unsigned short* gw = w_bf + (size_t)(wrow_base + row) * 1024 + kb * 32 + chunk * 8;
      __builtin_amdgcn_global_load_lds(
          (const __attribute__((address_space(1))) void*)gx,
          (__attribute__((address_space(3))) void*)&Xt[(i * 64 + w * 16) * 32], 16, 0, 0);
      __builtin_amdgcn_global_load_lds(
          (const __attribute__((address_space(1))) void*)gw,
          (__attribute__((address_space(3))) void*)&Wt[(i * 64 + w * 16) * 32], 16, 0, 0);
    }
    asm volatile("s_waitcnt vmcnt(0)" ::: "memory");
    __syncthreads();

    bf16x8 af[4], bfr[4];
#pragma unroll
    for (int m = 0; m < 4; ++m) {
      int ar = wr * 64 + m * 16 + c;
      int br = wc * 64 + m * 16 + c;
      int ach = g ^ ((ar >> 1) & 3);
      int bch = g ^ ((br >> 1) & 3);
      if (VAR == 0) {
        af[m]  = *(const bf16x8*)(&Wt[ar * 32 + ach * 8]);
        bfr[m] = *(const bf16x8*)(&Xt[br * 32 + bch * 8]);
      } else {
        af[m]  = *(const bf16x8*)(&Xt[ar * 32 + ach * 8]);
        bfr[m] = *(const bf16x8*)(&Wt[br * 32 + bch * 8]);
      }
    }
#pragma unroll
    for (int m = 0; m < 4; ++m)
#pragma unroll
      for (int n = 0; n < 4; ++n)
        acc[m][n] = MFMA(af[m], bfr[n], acc[m][n], 0, 0, 0);
  }

  const float QSC = 0.125f * 1.44269504088896340736f; // 1/sqrt(64) * log2(e)
  if (VAR == 0) {
    const bool isq = (et < 8);
#pragma unroll
    for (int m = 0; m < 4; ++m) {
      int e0 = et * 128 + wr * 64 + m * 16 + g * 4;
      int eh = e0 & 1023;
      int h = eh >> 6, d0 = eh & 63;
#pragma unroll
      for (int n = 0; n < 4; ++n) {
        int s = st * 128 + wc * 64 + n * 16 + c;
        int b = s >> 11, sl = s & 2047;
        u16x4 p;
        if (isq) {
#pragma unroll
          for (int r = 0; r < 4; ++r) p[r] = f2b((acc[m][n][r] + bq[eh + r]) * QSC);
          *(u16x4*)(&q_ws[((size_t)(b * NH + h) * SEQ + sl) * 64 + d0]) = p;
        } else {
#pragma unroll
          for (int r = 0; r < 4; ++r) p[r] = f2b(acc[m][n][r] + bk[eh + r]);
          *(u16x4*)(&k_ws[((size_t)(b * NH + h) * SEQ + sl) * 64 + d0]) = p;
        }
      }
    }
  } else {
#pragma unroll
    for (int m = 0; m < 4; ++m) {
      int s0 = st * 128 + wr * 64 + m * 16 + g * 4;
      int b = s0 >> 11, sl0 = s0 & 2047;
#pragma unroll
      for (int n = 0; n < 4; ++n) {
        int e = et * 128 + wc * 64 + n * 16 + c;
        int h = e >> 6, d = e & 63;
        float bias = bv[e];
        u16x4 p;
#pragma unroll
        for (int r = 0; r < 4; ++r) p[r] = f2b(acc[m][n][r] + bias);
        *(u16x4*)(&vt_ws[((size_t)(b * NH + h) * 64 + d) * SEQ + sl0]) = p;
      }
    }
  }
}

// ---------------------------------------------------------------------------
// Kernel 2: fused attention — two staged passes, both on the proven
// dbuf + global_load_lds + counted-vmcnt template. Block = 4 waves x 64 q.
//  pass A (K only, 8KB/tile): QK^T (swapped, A=K B=Q) -> exp2 -> lane-local
//    rowsum; vmcnt(0)+barrier per tile (2 loads in flight). Gives invl.
//  pass B (K+V, 16KB/tile): QK^T -> exp2 -> normalized probs from f32 regs
//    (NT f32x4) + unnormalized bf16 P via per-wave swizzled scratch -> PV.
//    vmcnt(16) per tile: retires ONLY the 4 staging loads (oldest); all 16
//    NT probs stores stay in flight across the barrier.
// XCD-swizzled grid: XCD owns 4 bh -> K/V working set 2MB, L2-resident.
// LDS 40KB -> 4 blocks/CU.
// ---------------------------------------------------------------------------
__global__ __launch_bounds__(256, 4) void attn_kernel(
    const unsigned short* __restrict__ q_ws, const unsigned short* __restrict__ k_ws,
    const unsigned short* __restrict__ vt_ws, float* __restrict__ out) {
  const int wg = blockIdx.x;
  const int xcd = wg & 7, idx = wg >> 3;
  const int bh = xcd * 4 + (idx & 3), qt = idx >> 2;  // XCD owns 4 bh
  const int tid = threadIdx.x;
  const int w = tid >> 6, l = tid & 63, c = l & 15, g = l >> 4;

  __shared__ unsigned short Kb[2][64 * 64];  // [k-row][d], swizzled, dbuf
  __shared__ unsigned short Vb[2][64 * 64];  // [d-row][k], swizzled, dbuf
  __shared__ unsigned short Ps[4][1024];     // per-wave P scratch, swizzled

  const unsigned short* qp = q_ws + ((size_t)bh * SEQ + qt * 64 + w * 16 + c) * 64 + g * 8;
  bf16x8 qf0 = *(const bf16x8*)(qp);
  bf16x8 qf1 = *(const bf16x8*)(qp + 32);

  const unsigned short* kbase = k_ws + (size_t)bh * SEQ * 64;   // row stride 64
  const unsigned short* vbase = vt_ws + (size_t)bh * 64 * SEQ;  // row stride SEQ

  // staging geometry: wave w stages rows [w*16, w*16+16); source col
  // pre-swizzled so linear LDS holds LDS(r,b) = G(r, b ^ ((r&7)<<4)).
  const int srow = l >> 3;                       // 0..7
  const int scol = ((l & 7) ^ srow) << 3;        // u16 units (16B granule)

#define STAGE_K(BUF, KT)                                                       \
  {                                                                            \
    const unsigned short* ks_ = kbase + ((size_t)(KT) * 64 + w * 16) * 64;     \
    __builtin_amdgcn_global_load_lds(                                          \
        (const __attribute__((address_space(1))) void*)(ks_ + (size_t)srow * 64 + scol), \
        (__attribute__((address_space(3))) void*)&Kb[BUF][(w * 16) * 64], 16, 0, 0);     \
    __builtin_amdgcn_global_load_lds(                                          \
        (const __attribute__((address_space(1))) void*)(ks_ + (size_t)(8 + srow) * 64 + scol), \
        (__attribute__((address_space(3))) void*)&Kb[BUF][(w * 16 + 8) * 64], 16, 0, 0); \
  }

#define STAGE_V(BUF, KT)                                                       \
  {                                                                            \
    const unsigned short* vs_ = vbase + (size_t)(w * 16) * SEQ + (KT) * 64;    \
    __builtin_amdgcn_global_load_lds(                                          \
        (const __attribute__((address_space(1))) void*)(vs_ + (size_t)srow * SEQ + scol), \
        (__attribute__((address_space(3))) void*)&Vb[BUF][(w * 16) * 64], 16, 0, 0);     \
    __builtin_amdgcn_global_load_lds(                                          \
        (const __attribute__((address_space(1))) void*)(vs_ + (size_t)(8 + srow) * SEQ + scol), \
        (__attribute__((address_space(3))) void*)&Vb[BUF][(w * 16 + 8) * 64], 16, 0, 0); \
  }

  const int sw   = (c & 7) << 4;   // byte swz for tile rows (row&7 == c&7)
  const int pswz = (c & 7) << 3;   // u16 swz for Ps

  // ======== pass A: rowsums on the staged pipeline (K only) ========
  float lsum = 0.f;
  STAGE_K(0, 0);
  asm volatile("s_waitcnt vmcnt(0)" ::: "memory");
  __builtin_amdgcn_s_barrier();
  __builtin_amdgcn_sched_barrier(0);

  for (int kt = 0; kt < 32; ++kt) {
    const int buf = kt & 1;
    if (kt < 31) STAGE_K(buf ^ 1, kt + 1);
    __builtin_amdgcn_sched_barrier(0);

    f32x4 sa[4];
#pragma unroll
    for (int s = 0; s < 4; ++s) {
      const unsigned short* kb = &Kb[buf][(s * 16 + c) * 64];
      bf16x8 k0 = *(const bf16x8*)(kb + (((g * 16) ^ sw) >> 1));
      bf16x8 k1 = *(const bf16x8*)(kb + (((64 + g * 16) ^ sw) >> 1));
      sa[s] = f32x4{0.f, 0.f, 0.f, 0.f};
      sa[s] = MFMA(k0, qf0, sa[s], 0, 0, 0);
      sa[s] = MFMA(k1, qf1, sa[s], 0, 0, 0);
    }
#pragma unroll
    for (int s = 0; s < 4; ++s)
#pragma unroll
      for (int r = 0; r < 4; ++r) lsum += exp2f(sa[s][r]);

    __builtin_amdgcn_sched_barrier(0);
    asm volatile("s_waitcnt vmcnt(0)" ::: "memory");
    __builtin_amdgcn_s_barrier();
    __builtin_amdgcn_sched_barrier(0);
  }
  lsum += __shfl_xor(lsum, 16);
  lsum += __shfl_xor(lsum, 32);
  const float inv = 1.f / lsum;          // for q-row = c

  // ======== pass B: probs + PV on the staged pipeline (K + V) ========
  f32x4 ctx[4];
#pragma unroll
  for (int f = 0; f < 4; ++f) ctx[f] = f32x4{0.f, 0.f, 0.f, 0.f};

  float* prbase = out + (size_t)2 * SEQ * 1024 +
                  ((size_t)bh * SEQ + qt * 64 + w * 16 + c) * SEQ;

  STAGE_K(0, 0); STAGE_V(0, 0);
  asm volatile("s_waitcnt vmcnt(0)" ::: "memory");
  __builtin_amdgcn_s_barrier();
  __builtin_amdgcn_sched_barrier(0);

  for (int kt = 0; kt < 32; ++kt) {
    const int buf = kt & 1;
    if (kt < 31) { STAGE_K(buf ^ 1, kt + 1); STAGE_V(buf ^ 1, kt + 1); }
    __builtin_amdgcn_sched_barrier(0);

    // ---- QK^T: A = K rows (s*16+c), B = Q
    f32x4 sa[4];
#pragma unroll
    for (int s = 0; s < 4; ++s) {
      const unsigned short* kb = &Kb[buf][(s * 16 + c) * 64];
      bf16x8 k0 = *(const bf16x8*)(kb + (((g * 16) ^ sw) >> 1));
      bf16x8 k1 = *(const bf16x8*)(kb + (((64 + g * 16) ^ sw) >> 1));
      sa[s] = f32x4{0.f, 0.f, 0.f, 0.f};
      sa[s] = MFMA(k0, qf0, sa[s], 0, 0, 0);
      sa[s] = MFMA(k1, qf1, sa[s], 0, 0, 0);
    }

    // ---- exp2 -> probs (normalized, f32 regs, NT) + unnorm bf16 -> Ps
#pragma unroll
    for (int s = 0; s < 4; ++s) {
      f32x4 pw;
      u16x4 pb;
#pragma unroll
      for (int r = 0; r < 4; ++r) {
        float p = exp2f(sa[s][r]);
        pw[r] = p * inv;
        pb[r] = f2b(p);
      }
      __builtin_nontemporal_store(pw, (f32x4*)(prbase + kt * 64 + s * 16 + g * 4));
      *(u16x4*)(&Ps[w][c * 64 + ((s * 16 + g * 4) ^ pswz)]) = pb;
    }

    // ---- PV: A = P (same-wave scratch), B = V^T
#pragma unroll
    for (int W = 0; W < 2; ++W) {
      bf16x8 pa = *(const bf16x8*)(&Ps[w][c * 64 + ((W * 32 + g * 8) ^ pswz)]);
#pragma unroll
      for (int f = 0; f < 4; ++f) {
        const unsigned short* vb = &Vb[buf][(f * 16 + c) * 64];
        bf16x8 vbf = *(const bf16x8*)(vb + (((W * 64 + g * 16) ^ sw) >> 1));
        ctx[f] = MFMA(pa, vbf, ctx[f], 0, 0, 0);
      }
    }

    __builtin_amdgcn_sched_barrier(0);
    // retire ONLY the 4 staging loads (oldest); 16 NT stores stay in flight
    asm volatile("s_waitcnt vmcnt(16)" ::: "memory");
    __builtin_amdgcn_s_barrier();
    __builtin_amdgcn_sched_barrier(0);
  }
#undef STAGE_K
#undef STAGE_V

  // ---- ctx epilogue: lane holds C[q = g*4+r][d = f*16+c]
  const int b = bh >> 4, h = bh & 15;
  float invq[4];
#pragma unroll
  for (int r = 0; r < 4; ++r) invq[r] = __shfl(inv, g * 4 + r);
#pragma unroll
  for (int f = 0; f < 4; ++f)
#pragma unroll
    for (int r = 0; r < 4; ++r) {
      int s = qt * 64 + w * 16 + g * 4 + r;
      out[((size_t)b * SEQ + s) * 1024 + h * 64 + f * 16 + c] = ctx[f][r] * invq[r];
    }
}

extern "C" void kernel_launch(void* const* d_in, const int* in_sizes, int n_in,
                              void* d_out, int out_size, void* d_ws, size_t ws_size,
                              hipStream_t stream) {
  (void)in_sizes; (void)n_in; (void)out_size; (void)ws_size;
  const float* x  = (const float*)d_in[0];
  const float* wq = (const float*)d_in[1];
  const float* bq = (const float*)d_in[2];
  const float* wk = (const float*)d_in[3];
  const float* bk = (const float*)d_in[4];
  const float* wv = (const float*)d_in[5];
  const float* bv = (const float*)d_in[6];

  unsigned short* xw_bf = (unsigned short*)d_ws;            // x_bf + w_bf
  unsigned short* x_bf  = xw_bf;
  unsigned short* w_bf  = xw_bf + 4194304;
  unsigned short* q_ws  = xw_bf + 7340032;                  // [32][2048][64]
  unsigned short* k_ws  = q_ws + 4194304;                   // [32][2048][64]
  unsigned short* vt_ws = k_ws + 4194304;                   // [32][64][2048]
  float* out = (float*)d_out;

  convert_kernel<<<3584, 256, 0, stream>>>(x, wq, wk, wv, xw_bf);
  gemm_qkv<0><<<dim3(32, 16), 256, 0, stream>>>(x_bf, w_bf, bq, bk, bv, q_ws, k_ws, vt_ws);
  gemm_qkv<1><<<dim3(32, 8), 256, 0, stream>>>(x_bf, w_bf, bq, bk, bv, q_ws, k_ws, vt_ws);
  attn_kernel<<<1024, 256, 0, stream>>>(q_ws, k_ws, vt_ws, out);
}

// Round 8
// 315.861 us; speedup vs baseline: 1.3201x; 1.0640x over previous
//
#include <hip/hip_runtime.h>
#include <cmath>

// Problem constants: B=2, H=16, S=2048, D=1024, dh=64
#define SEQ 2048
#define NH  16

using bf16x8 = __attribute__((ext_vector_type(8))) short;
using f32x4  = __attribute__((ext_vector_type(4))) float;
using u16x8  = __attribute__((ext_vector_type(8))) unsigned short;
using u16x4  = __attribute__((ext_vector_type(4))) unsigned short;

#define MFMA __builtin_amdgcn_mfma_f32_16x16x32_bf16

static __device__ __forceinline__ unsigned short f2b(float f) {
  unsigned int x = __float_as_uint(f);
  x += 0x7fffu + ((x >> 16) & 1u);
  return (unsigned short)(x >> 16);
}

static __device__ __forceinline__ u16x8 cvt8(f32x4 a, f32x4 b) {
  u16x8 o;
  o[0] = f2b(a[0]); o[1] = f2b(a[1]); o[2] = f2b(a[2]); o[3] = f2b(a[3]);
  o[4] = f2b(b[0]); o[5] = f2b(b[1]); o[6] = f2b(b[2]); o[7] = f2b(b[3]);
  return o;
}

// ---------------------------------------------------------------------------
// Kernel 0: one-shot f32 -> bf16 convert of x and [Wq;Wk;Wv] into workspace.
// ---------------------------------------------------------------------------
__global__ __launch_bounds__(256) void convert_kernel(
    const float* __restrict__ x, const float* __restrict__ wq,
    const float* __restrict__ wk, const float* __restrict__ wv,
    unsigned short* __restrict__ dst) {
  int bid = blockIdx.x;
  const float* src;
  size_t off;
  if (bid < 2048)      { src = x;  off = (size_t)bid * 2048; }
  else if (bid < 2560) { src = wq; off = (size_t)(bid - 2048) * 2048; dst += 4194304; }
  else if (bid < 3072) { src = wk; off = (size_t)(bid - 2560) * 2048; dst += 4194304 + 1048576; }
  else                 { src = wv; off = (size_t)(bid - 3072) * 2048; dst += 4194304 + 2097152; }
  size_t i = off + (size_t)threadIdx.x * 8;
  f32x4 a = *(const f32x4*)(src + i);
  f32x4 b = *(const f32x4*)(src + i + 4);
  *(u16x8*)(dst + i) = cvt8(a, b);
}

// ---------------------------------------------------------------------------
// Kernel 1: m97-structure bf16 GEMM, 128x128 tile, BK=32, 4 waves (2x2),
// global_load_lds width-16 staging, source-swizzled LDS. (unchanged)
// ---------------------------------------------------------------------------
template <int VAR>
__global__ __launch_bounds__(256) void gemm_qkv(
    const unsigned short* __restrict__ x_bf,   // [4096][1024]
    const unsigned short* __restrict__ w_bf,   // [3072][1024] = [wq;wk;wv]
    const float* __restrict__ bq, const float* __restrict__ bk,
    const float* __restrict__ bv,
    unsigned short* __restrict__ q_ws, unsigned short* __restrict__ k_ws,
    unsigned short* __restrict__ vt_ws) {
  const int st  = blockIdx.x;
  const int et  = blockIdx.y;
  const int tid = threadIdx.x;
  const int w = tid >> 6, l = tid & 63, c = l & 15, g = l >> 4;
  const int wr = w >> 1, wc = w & 1;

  __shared__ unsigned short Xt[128 * 32];
  __shared__ unsigned short Wt[128 * 32];

  const int wrow_base = (VAR == 0 ? et * 128 : 2048 + et * 128);

  f32x4 acc[4][4];
#pragma unroll
  for (int m = 0; m < 4; ++m)
#pragma unroll
    for (int n = 0; n < 4; ++n) acc[m][n] = f32x4{0.f, 0.f, 0.f, 0.f};

  for (int kb = 0; kb < 32; ++kb) {
    __syncthreads();
#pragma unroll
    for (int i = 0; i < 2; ++i) {
      int row   = i * 64 + w * 16 + (l >> 2);
      int chunk = (l & 3) ^ ((row >> 1) & 3);
      const unsigned short* gx = x_bf + (size_t)(st * 128 + row) * 1024 + kb * 32 + chunk * 8;
      const unsigned short* gw = w_bf + (size_t)(wrow_base + row) * 1024 + kb * 32 + chunk * 8;
      __builtin_amdgcn_global_load_lds(
          (const __attribute__((address_space(1))) void*)gx,
          (__attribute__((address_space(3))) void*)&Xt[(i * 64 + w * 16) * 32], 16, 0, 0);
      __builtin_amdgcn_global_load_lds(
          (const __attribute__((address_space(1))) void*)gw,
          (__attribute__((address_space(3))) void*)&Wt[(i * 64 + w * 16) * 32], 16, 0, 0);
    }
    asm volatile("s_waitcnt vmcnt(0)" ::: "memory");
    __syncthreads();

    bf16x8 af[4], bfr[4];
#pragma unroll
    for (int m = 0; m < 4; ++m) {
      int ar = wr * 64 + m * 16 + c;
      int br = wc * 64 + m * 16 + c;
      int ach = g ^ ((ar >> 1) & 3);
      int bch = g ^ ((br >> 1) & 3);
      if (VAR == 0) {
        af[m]  = *(const bf16x8*)(&Wt[ar * 32 + ach * 8]);
        bfr[m] = *(const bf16x8*)(&Xt[br * 32 + bch * 8]);
      } else {
        af[m]  = *(const bf16x8*)(&Xt[ar * 32 + ach * 8]);
        bfr[m] = *(const bf16x8*)(&Wt[br * 32 + bch * 8]);
      }
    }
#pragma unroll
    for (int m = 0; m < 4; ++m)
#pragma unroll
      for (int n = 0; n < 4; ++n)
        acc[m][n] = MFMA(af[m], bfr[n], acc[m][n], 0, 0, 0);
  }

  const float QSC = 0.125f * 1.44269504088896340736f; // 1/sqrt(64) * log2(e)
  if (VAR == 0) {
    const bool isq = (et < 8);
#pragma unroll
    for (int m = 0; m < 4; ++m) {
      int e0 = et * 128 + wr * 64 + m * 16 + g * 4;
      int eh = e0 & 1023;
      int h = eh >> 6, d0 = eh & 63;
#pragma unroll
      for (int n = 0; n < 4; ++n) {
        int s = st * 128 + wc * 64 + n * 16 + c;
        int b = s >> 11, sl = s & 2047;
        u16x4 p;
        if (isq) {
#pragma unroll
          for (int r = 0; r < 4; ++r) p[r] = f2b((acc[m][n][r] + bq[eh + r]) * QSC);
          *(u16x4*)(&q_ws[((size_t)(b * NH + h) * SEQ + sl) * 64 + d0]) = p;
        } else {
#pragma unroll
          for (int r = 0; r < 4; ++r) p[r] = f2b(acc[m][n][r] + bk[eh + r]);
          *(u16x4*)(&k_ws[((size_t)(b * NH + h) * SEQ + sl) * 64 + d0]) = p;
        }
      }
    }
  } else {
#pragma unroll
    for (int m = 0; m < 4; ++m) {
      int s0 = st * 128 + wr * 64 + m * 16 + g * 4;
      int b = s0 >> 11, sl0 = s0 & 2047;
#pragma unroll
      for (int n = 0; n < 4; ++n) {
        int e = et * 128 + wc * 64 + n * 16 + c;
        int h = e >> 6, d = e & 63;
        float bias = bv[e];
        u16x4 p;
#pragma unroll
        for (int r = 0; r < 4; ++r) p[r] = f2b(acc[m][n][r] + bias);
        *(u16x4*)(&vt_ws[((size_t)(b * NH + h) * 64 + d) * SEQ + sl0]) = p;
      }
    }
  }
}

// ---------------------------------------------------------------------------
// Kernel 2: fused attention — two staged passes, 3-deep buffers, stage-2-ahead,
// exactly-counted vmcnt (in-order retirement semantics). Block = 4 waves x 64q.
//  pass A (K only): body kt = [vmcnt(2) wait: K(kt) staged 2 bodies ago]
//    [barrier] [STAGE K(kt+2)] [QK^T + exp2 -> lane rowsum]. No stores.
//  pass B (K+V+probs): body kt = [vmcnt(20) wait (kt=0: vmcnt(4)): retires
//    KV(kt), leaves KV(kt+1)+stores(kt-1) in flight] [barrier]
//    [STAGE KV(kt+2)] [QK^T -> exp2 -> NT normalized probs from regs +
//    bf16 P via per-wave swizzled Ps -> PV].
// XCD-swizzled grid (XCD owns 4 bh). LDS 56KB -> 2 blocks/CU.
// ---------------------------------------------------------------------------
__global__ __launch_bounds__(256, 2) void attn_kernel(
    const unsigned short* __restrict__ q_ws, const unsigned short* __restrict__ k_ws,
    const unsigned short* __restrict__ vt_ws, float* __restrict__ out) {
  const int wg = blockIdx.x;
  const int xcd = wg & 7, idx = wg >> 3;
  const int bh = xcd * 4 + (idx & 3), qt = idx >> 2;  // XCD owns 4 bh
  const int tid = threadIdx.x;
  const int w = tid >> 6, l = tid & 63, c = l & 15, g = l >> 4;

  __shared__ unsigned short Ka[3][64 * 64];  // [k-row][d], swizzled, 3-deep
  __shared__ unsigned short Va[3][64 * 64];  // [d-row][k], swizzled, 3-deep
  __shared__ unsigned short Ps[4][1024];     // per-wave P scratch, swizzled

  const unsigned short* qp = q_ws + ((size_t)bh * SEQ + qt * 64 + w * 16 + c) * 64 + g * 8;
  bf16x8 qf0 = *(const bf16x8*)(qp);
  bf16x8 qf1 = *(const bf16x8*)(qp + 32);

  const unsigned short* kbase = k_ws + (size_t)bh * SEQ * 64;   // row stride 64
  const unsigned short* vbase = vt_ws + (size_t)bh * 64 * SEQ;  // row stride SEQ

  // staging geometry: wave w stages rows [w*16, w*16+16); source col
  // pre-swizzled so linear LDS holds LDS(r,b) = G(r, b ^ ((r&7)<<4)).
  const int srow = l >> 3;                       // 0..7
  const int scol = ((l & 7) ^ srow) << 3;        // u16 units (16B granule)

#define STAGE_K(SLOT, KT)                                                      \
  {                                                                            \
    const unsigned short* ks_ = kbase + ((size_t)(KT) * 64 + w * 16) * 64;     \
    __builtin_amdgcn_global_load_lds(                                          \
        (const __attribute__((address_space(1))) void*)(ks_ + (size_t)srow * 64 + scol), \
        (__attribute__((address_space(3))) void*)&Ka[SLOT][(w * 16) * 64], 16, 0, 0);    \
    __builtin_amdgcn_global_load_lds(                                          \
        (const __attribute__((address_space(1))) void*)(ks_ + (size_t)(8 + srow) * 64 + scol), \
        (__attribute__((address_space(3))) void*)&Ka[SLOT][(w * 16 + 8) * 64], 16, 0, 0); \
  }

#define STAGE_V(SLOT, KT)                                                      \
  {                                                                            \
    const unsigned short* vs_ = vbase + (size_t)(w * 16) * SEQ + (KT) * 64;    \
    __builtin_amdgcn_global_load_lds(                                          \
        (const __attribute__((address_space(1))) void*)(vs_ + (size_t)srow * SEQ + scol), \
        (__attribute__((address_space(3))) void*)&Va[SLOT][(w * 16) * 64], 16, 0, 0);    \
    __builtin_amdgcn_global_load_lds(                                          \
        (const __attribute__((address_space(1))) void*)(vs_ + (size_t)(8 + srow) * SEQ + scol), \
        (__attribute__((address_space(3))) void*)&Va[SLOT][(w * 16 + 8) * 64], 16, 0, 0); \
  }

  const int sw   = (c & 7) << 4;   // byte swz for tile rows (row&7 == c&7)
  const int pswz = (c & 7) << 3;   // u16 swz for Ps

  // ======== pass A: rowsums, 3-deep K pipeline ========
  float lsum = 0.f;
  STAGE_K(0, 0);
  STAGE_K(1, 1);

  for (int kt = 0; kt < 32; ++kt) {
    const int slot = kt % 3;
    asm volatile("s_waitcnt vmcnt(2)" ::: "memory");  // K(kt) done; K(kt+1) in flight
    __builtin_amdgcn_s_barrier();
    __builtin_amdgcn_sched_barrier(0);
    if (kt < 30) STAGE_K((kt + 2) % 3, kt + 2);
    __builtin_amdgcn_sched_barrier(0);

    f32x4 sa[4];
#pragma unroll
    for (int s = 0; s < 4; ++s) {
      const unsigned short* kb = &Ka[slot][(s * 16 + c) * 64];
      bf16x8 k0 = *(const bf16x8*)(kb + (((g * 16) ^ sw) >> 1));
      bf16x8 k1 = *(const bf16x8*)(kb + (((64 + g * 16) ^ sw) >> 1));
      sa[s] = f32x4{0.f, 0.f, 0.f, 0.f};
      sa[s] = MFMA(k0, qf0, sa[s], 0, 0, 0);
      sa[s] = MFMA(k1, qf1, sa[s], 0, 0, 0);
    }
#pragma unroll
    for (int s = 0; s < 4; ++s)
#pragma unroll
      for (int r = 0; r < 4; ++r) lsum += exp2f(sa[s][r]);
  }
  lsum += __shfl_xor(lsum, 16);
  lsum += __shfl_xor(lsum, 32);
  const float inv = 1.f / lsum;          // for q-row = c

  // ======== pass B: probs + PV, 3-deep K+V pipeline ========
  f32x4 ctx[4];
#pragma unroll
  for (int f = 0; f < 4; ++f) ctx[f] = f32x4{0.f, 0.f, 0.f, 0.f};

  float* prbase = out + (size_t)2 * SEQ * 1024 +
                  ((size_t)bh * SEQ + qt * 64 + w * 16 + c) * SEQ;

  __builtin_amdgcn_s_barrier();          // pass A readers done before restaging
  STAGE_K(0, 0); STAGE_V(0, 0);
  STAGE_K(1, 1); STAGE_V(1, 1);

  for (int kt = 0; kt < 32; ++kt) {
    const int slot = kt % 3;
    // in-order vmcnt: retire KV(kt); leave KV(kt+1)[4] + stores(kt-1)[16]
    if (kt == 0) {
      asm volatile("s_waitcnt vmcnt(4)" ::: "memory");
    } else {
      asm volatile("s_waitcnt vmcnt(20)" ::: "memory");
    }
    __builtin_amdgcn_s_barrier();
    __builtin_amdgcn_sched_barrier(0);
    if (kt < 30) { STAGE_K((kt + 2) % 3, kt + 2); STAGE_V((kt + 2) % 3, kt + 2); }
    __builtin_amdgcn_sched_barrier(0);

    // ---- QK^T: A = K rows (s*16+c), B = Q
    f32x4 sa[4];
#pragma unroll
    for (int s = 0; s < 4; ++s) {
      const unsigned short* kb = &Ka[slot][(s * 16 + c) * 64];
      bf16x8 k0 = *(const bf16x8*)(kb + (((g * 16) ^ sw) >> 1));
      bf16x8 k1 = *(const bf16x8*)(kb + (((64 + g * 16) ^ sw) >> 1));
      sa[s] = f32x4{0.f, 0.f, 0.f, 0.f};
      sa[s] = MFMA(k0, qf0, sa[s], 0, 0, 0);
      sa[s] = MFMA(k1, qf1, sa[s], 0, 0, 0);
    }

    // ---- exp2 -> probs (normalized, f32 regs, NT) + unnorm bf16 -> Ps
#pragma unroll
    for (int s = 0; s < 4; ++s) {
      f32x4 pw;
      u16x4 pb;
#pragma unroll
      for (int r = 0; r < 4; ++r) {
        float p = exp2f(sa[s][r]);
        pw[r] = p * inv;
        pb[r] = f2b(p);
      }
      __builtin_nontemporal_store(pw, (f32x4*)(prbase + kt * 64 + s * 16 + g * 4));
      *(u16x4*)(&Ps[w][c * 64 + ((s * 16 + g * 4) ^ pswz)]) = pb;
    }

    // ---- PV: A = P (same-wave scratch), B = V^T
#pragma unroll
    for (int W = 0; W < 2; ++W) {
      bf16x8 pa = *(const bf16x8*)(&Ps[w][c * 64 + ((W * 32 + g * 8) ^ pswz)]);
#pragma unroll
      for (int f = 0; f < 4; ++f) {
        const unsigned short* vb = &Va[slot][(f * 16 + c) * 64];
        bf16x8 vbf = *(const bf16x8*)(vb + (((W * 64 + g * 16) ^ sw) >> 1));
        ctx[f] = MFMA(pa, vbf, ctx[f], 0, 0, 0);
      }
    }
  }
#undef STAGE_K
#undef STAGE_V

  // ---- ctx epilogue: lane holds C[q = g*4+r][d = f*16+c]
  const int b = bh >> 4, h = bh & 15;
  float invq[4];
#pragma unroll
  for (int r = 0; r < 4; ++r) invq[r] = __shfl(inv, g * 4 + r);
#pragma unroll
  for (int f = 0; f < 4; ++f)
#pragma unroll
    for (int r = 0; r < 4; ++r) {
      int s = qt * 64 + w * 16 + g * 4 + r;
      out[((size_t)b * SEQ + s) * 1024 + h * 64 + f * 16 + c] = ctx[f][r] * invq[r];
    }
}

extern "C" void kernel_launch(void* const* d_in, const int* in_sizes, int n_in,
                              void* d_out, int out_size, void* d_ws, size_t ws_size,
                              hipStream_t stream) {
  (void)in_sizes; (void)n_in; (void)out_size; (void)ws_size;
  const float* x  = (const float*)d_in[0];
  const float* wq = (const float*)d_in[1];
  const float* bq = (const float*)d_in[2];
  const float* wk = (const float*)d_in[3];
  const float* bk = (const float*)d_in[4];
  const float* wv = (const float*)d_in[5];
  const float* bv = (const float*)d_in[6];

  unsigned short* xw_bf = (unsigned short*)d_ws;            // x_bf + w_bf
  unsigned short* x_bf  = xw_bf;
  unsigned short* w_bf  = xw_bf + 4194304;
  unsigned short* q_ws  = xw_bf + 7340032;                  // [32][2048][64]
  unsigned short* k_ws  = q_ws + 4194304;                   // [32][2048][64]
  unsigned short* vt_ws = k_ws + 4194304;                   // [32][64][2048]
  float* out = (float*)d_out;

  convert_kernel<<<3584, 256, 0, stream>>>(x, wq, wk, wv, xw_bf);
  gemm_qkv<0><<<dim3(32, 16), 256, 0, stream>>>(x_bf, w_bf, bq, bk, bv, q_ws, k_ws, vt_ws);
  gemm_qkv<1><<<dim3(32, 8), 256, 0, stream>>>(x_bf, w_bf, bq, bk, bv, q_ws, k_ws, vt_ws);
  attn_kernel<<<1024, 256, 0, stream>>>(q_ws, k_ws, vt_ws, out);
}

// Round 9
// 276.507 us; speedup vs baseline: 1.5080x; 1.1423x over previous
//
#include <hip/hip_runtime.h>
#include <cmath>

// Problem constants: B=2, H=16, S=2048, D=1024, dh=64
#define SEQ 2048
#define NH  16

using bf16x8 = __attribute__((ext_vector_type(8))) short;
using f32x4  = __attribute__((ext_vector_type(4))) float;
using u16x8  = __attribute__((ext_vector_type(8))) unsigned short;
using u16x4  = __attribute__((ext_vector_type(4))) unsigned short;

#define MFMA __builtin_amdgcn_mfma_f32_16x16x32_bf16

static __device__ __forceinline__ unsigned short f2b(float f) {
  unsigned int x = __float_as_uint(f);
  x += 0x7fffu + ((x >> 16) & 1u);
  return (unsigned short)(x >> 16);
}

static __device__ __forceinline__ u16x8 cvt8(f32x4 a, f32x4 b) {
  u16x8 o;
  o[0] = f2b(a[0]); o[1] = f2b(a[1]); o[2] = f2b(a[2]); o[3] = f2b(a[3]);
  o[4] = f2b(b[0]); o[5] = f2b(b[1]); o[6] = f2b(b[2]); o[7] = f2b(b[3]);
  return o;
}

// ---------------------------------------------------------------------------
// Kernel 0: one-shot f32 -> bf16 convert of x and [Wq;Wk;Wv] into workspace.
// ---------------------------------------------------------------------------
__global__ __launch_bounds__(256) void convert_kernel(
    const float* __restrict__ x, const float* __restrict__ wq,
    const float* __restrict__ wk, const float* __restrict__ wv,
    unsigned short* __restrict__ dst) {
  int bid = blockIdx.x;
  const float* src;
  size_t off;
  if (bid < 2048)      { src = x;  off = (size_t)bid * 2048; }
  else if (bid < 2560) { src = wq; off = (size_t)(bid - 2048) * 2048; dst += 4194304; }
  else if (bid < 3072) { src = wk; off = (size_t)(bid - 2560) * 2048; dst += 4194304 + 1048576; }
  else                 { src = wv; off = (size_t)(bid - 3072) * 2048; dst += 4194304 + 2097152; }
  size_t i = off + (size_t)threadIdx.x * 8;
  f32x4 a = *(const f32x4*)(src + i);
  f32x4 b = *(const f32x4*)(src + i + 4);
  *(u16x8*)(dst + i) = cvt8(a, b);
}

// ---------------------------------------------------------------------------
// Kernel 1: m97-structure bf16 GEMM, 128x128 tile, BK=32, 4 waves (2x2),
// global_load_lds width-16 staging, source-swizzled LDS. (unchanged)
// ---------------------------------------------------------------------------
template <int VAR>
__global__ __launch_bounds__(256) void gemm_qkv(
    const unsigned short* __restrict__ x_bf,   // [4096][1024]
    const unsigned short* __restrict__ w_bf,   // [3072][1024] = [wq;wk;wv]
    const float* __restrict__ bq, const float* __restrict__ bk,
    const float* __restrict__ bv,
    unsigned short* __restrict__ q_ws, unsigned short* __restrict__ k_ws,
    unsigned short* __restrict__ vt_ws) {
  const int st  = blockIdx.x;
  const int et  = blockIdx.y;
  const int tid = threadIdx.x;
  const int w = tid >> 6, l = tid & 63, c = l & 15, g = l >> 4;
  const int wr = w >> 1, wc = w & 1;

  __shared__ unsigned short Xt[128 * 32];
  __shared__ unsigned short Wt[128 * 32];

  const int wrow_base = (VAR == 0 ? et * 128 : 2048 + et * 128);

  f32x4 acc[4][4];
#pragma unroll
  for (int m = 0; m < 4; ++m)
#pragma unroll
    for (int n = 0; n < 4; ++n) acc[m][n] = f32x4{0.f, 0.f, 0.f, 0.f};

  for (int kb = 0; kb < 32; ++kb) {
    __syncthreads();
#pragma unroll
    for (int i = 0; i < 2; ++i) {
      int row   = i * 64 + w * 16 + (l >> 2);
      int chunk = (l & 3) ^ ((row >> 1) & 3);
      const unsigned short* gx = x_bf + (size_t)(st * 128 + row) * 1024 + kb * 32 + chunk * 8;
      const unsigned short* gw = w_bf + (size_t)(wrow_base + row) * 1024 + kb * 32 + chunk * 8;
      __builtin_amdgcn_global_load_lds(
          (const __attribute__((address_space(1))) void*)gx,
          (__attribute__((address_space(3))) void*)&Xt[(i * 64 + w * 16) * 32], 16, 0, 0);
      __builtin_amdgcn_global_load_lds(
          (const __attribute__((address_space(1))) void*)gw,
          (__attribute__((address_space(3))) void*)&Wt[(i * 64 + w * 16) * 32], 16, 0, 0);
    }
    asm volatile("s_waitcnt vmcnt(0)" ::: "memory");
    __syncthreads();

    bf16x8 af[4], bfr[4];
#pragma unroll
    for (int m = 0; m < 4; ++m) {
      int ar = wr * 64 + m * 16 + c;
      int br = wc * 64 + m * 16 + c;
      int ach = g ^ ((ar >> 1) & 3);
      int bch = g ^ ((br >> 1) & 3);
      if (VAR == 0) {
        af[m]  = *(const bf16x8*)(&Wt[ar * 32 + ach * 8]);
        bfr[m] = *(const bf16x8*)(&Xt[br * 32 + bch * 8]);
      } else {
        af[m]  = *(const bf16x8*)(&Xt[ar * 32 + ach * 8]);
        bfr[m] = *(const bf16x8*)(&Wt[br * 32 + bch * 8]);
      }
    }
#pragma unroll
    for (int m = 0; m < 4; ++m)
#pragma unroll
      for (int n = 0; n < 4; ++n)
        acc[m][n] = MFMA(af[m], bfr[n], acc[m][n], 0, 0, 0);
  }

  const float QSC = 0.125f * 1.44269504088896340736f; // 1/sqrt(64) * log2(e)
  if (VAR == 0) {
    const bool isq = (et < 8);
#pragma unroll
    for (int m = 0; m < 4; ++m) {
      int e0 = et * 128 + wr * 64 + m * 16 + g * 4;
      int eh = e0 & 1023;
      int h = eh >> 6, d0 = eh & 63;
#pragma unroll
      for (int n = 0; n < 4; ++n) {
        int s = st * 128 + wc * 64 + n * 16 + c;
        int b = s >> 11, sl = s & 2047;
        u16x4 p;
        if (isq) {
#pragma unroll
          for (int r = 0; r < 4; ++r) p[r] = f2b((acc[m][n][r] + bq[eh + r]) * QSC);
          *(u16x4*)(&q_ws[((size_t)(b * NH + h) * SEQ + sl) * 64 + d0]) = p;
        } else {
#pragma unroll
          for (int r = 0; r < 4; ++r) p[r] = f2b(acc[m][n][r] + bk[eh + r]);
          *(u16x4*)(&k_ws[((size_t)(b * NH + h) * SEQ + sl) * 64 + d0]) = p;
        }
      }
    }
  } else {
#pragma unroll
    for (int m = 0; m < 4; ++m) {
      int s0 = st * 128 + wr * 64 + m * 16 + g * 4;
      int b = s0 >> 11, sl0 = s0 & 2047;
#pragma unroll
      for (int n = 0; n < 4; ++n) {
        int e = et * 128 + wc * 64 + n * 16 + c;
        int h = e >> 6, d = e & 63;
        float bias = bv[e];
        u16x4 p;
#pragma unroll
        for (int r = 0; r < 4; ++r) p[r] = f2b(acc[m][n][r] + bias);
        *(u16x4*)(&vt_ws[((size_t)(b * NH + h) * 64 + d) * SEQ + sl0]) = p;
      }
    }
  }
}

// Shared staging geometry for the attention kernels: wave w stages rows
// [w*16, w*16+16) of a 64x64 bf16 tile; the source column is pre-swizzled so
// linear global_load_lds leaves LDS(r,b) = G(r, b ^ ((r&7)<<4)).
#define STAGE_TILE(LDS, SLOT, SRC, STRIDE)                                     \
  {                                                                            \
    __builtin_amdgcn_global_load_lds(                                          \
        (const __attribute__((address_space(1))) void*)((SRC) + (size_t)srow * (STRIDE) + scol), \
        (__attribute__((address_space(3))) void*)&LDS[SLOT][(w * 16) * 64], 16, 0, 0);   \
    __builtin_amdgcn_global_load_lds(                                          \
        (const __attribute__((address_space(1))) void*)((SRC) + (size_t)(8 + srow) * (STRIDE) + scol), \
        (__attribute__((address_space(3))) void*)&LDS[SLOT][(w * 16 + 8) * 64], 16, 0, 0); \
  }

// ---------------------------------------------------------------------------
// Kernel 2a: rowsum pass. Block = 4 waves x 64 q (wave owns 16 q, full K
// sweep). Double-buffered K staging, compiler-managed __syncthreads (m97
// 2-phase). LDS 16KB -> 8 blocks/CU: inter-block TLP hides barrier drain.
// invl[bh][q] = 1 / sum_k exp2(q.k)  (q pre-scaled to log2 domain).
// ---------------------------------------------------------------------------
__global__ __launch_bounds__(256) void rowsum_kernel(
    const unsigned short* __restrict__ q_ws, const unsigned short* __restrict__ k_ws,
    float* __restrict__ invl_ws) {
  const int wg = blockIdx.x;
  const int xcd = wg & 7, idx = wg >> 3;
  const int bh = xcd * 4 + (idx & 3), qt = idx >> 2;  // XCD owns 4 bh
  const int tid = threadIdx.x;
  const int w = tid >> 6, l = tid & 63, c = l & 15, g = l >> 4;

  __shared__ unsigned short Ka[2][64 * 64];

  const unsigned short* qp = q_ws + ((size_t)bh * SEQ + qt * 64 + w * 16 + c) * 64 + g * 8;
  bf16x8 qf0 = *(const bf16x8*)(qp);
  bf16x8 qf1 = *(const bf16x8*)(qp + 32);

  const unsigned short* kbase = k_ws + (size_t)bh * SEQ * 64;
  const int srow = l >> 3;
  const int scol = ((l & 7) ^ srow) << 3;
  const int sw = (c & 7) << 4;

  STAGE_TILE(Ka, 0, kbase + ((size_t)0 * 64 + w * 16) * 64, 64);
  __syncthreads();

  float lsum = 0.f;
  for (int kt = 0; kt < 32; ++kt) {
    const int buf = kt & 1;
    if (kt < 31)
      STAGE_TILE(Ka, buf ^ 1, kbase + ((size_t)(kt + 1) * 64 + w * 16) * 64, 64);

    f32x4 sa[4];
#pragma unroll
    for (int s = 0; s < 4; ++s) {
      const unsigned short* kb = &Ka[buf][(s * 16 + c) * 64];
      bf16x8 k0 = *(const bf16x8*)(kb + (((g * 16) ^ sw) >> 1));
      bf16x8 k1 = *(const bf16x8*)(kb + (((64 + g * 16) ^ sw) >> 1));
      sa[s] = f32x4{0.f, 0.f, 0.f, 0.f};
      sa[s] = MFMA(k0, qf0, sa[s], 0, 0, 0);
      sa[s] = MFMA(k1, qf1, sa[s], 0, 0, 0);
    }
#pragma unroll
    for (int s = 0; s < 4; ++s)
#pragma unroll
      for (int r = 0; r < 4; ++r) lsum += exp2f(sa[s][r]);

    __syncthreads();
  }
  lsum += __shfl_xor(lsum, 16);
  lsum += __shfl_xor(lsum, 32);
  if (g == 0) invl_ws[(size_t)bh * SEQ + qt * 64 + w * 16 + c] = 1.f / lsum;
}

// ---------------------------------------------------------------------------
// Kernel 2b: probs + PV pass. Same block shape. Double-buffered K+V staging,
// compiler-managed __syncthreads. QK^T (swapped, A=K B=Q) -> exp2 ->
// normalized probs written straight from f32 regs (plain f32x4, coalesced
// 64B runs merging into full lines across the s-loop) + unnormalized bf16 P
// via per-wave swizzled scratch -> PV with V^T B-frags. LDS 40KB -> 4
// blocks/CU.
// ---------------------------------------------------------------------------
__global__ __launch_bounds__(256, 4) void attnpv_kernel(
    const unsigned short* __restrict__ q_ws, const unsigned short* __restrict__ k_ws,
    const unsigned short* __restrict__ vt_ws, const float* __restrict__ invl_ws,
    float* __restrict__ out) {
  const int wg = blockIdx.x;
  const int xcd = wg & 7, idx = wg >> 3;
  const int bh = xcd * 4 + (idx & 3), qt = idx >> 2;  // XCD owns 4 bh
  const int tid = threadIdx.x;
  const int w = tid >> 6, l = tid & 63, c = l & 15, g = l >> 4;

  __shared__ unsigned short Ka[2][64 * 64];  // [k-row][d], swizzled
  __shared__ unsigned short Va[2][64 * 64];  // [d-row][k], swizzled
  __shared__ unsigned short Ps[4][1024];     // per-wave P scratch, swizzled

  const unsigned short* qp = q_ws + ((size_t)bh * SEQ + qt * 64 + w * 16 + c) * 64 + g * 8;
  bf16x8 qf0 = *(const bf16x8*)(qp);
  bf16x8 qf1 = *(const bf16x8*)(qp + 32);
  const float inv = invl_ws[(size_t)bh * SEQ + qt * 64 + w * 16 + c];

  const unsigned short* kbase = k_ws + (size_t)bh * SEQ * 64;   // row stride 64
  const unsigned short* vbase = vt_ws + (size_t)bh * 64 * SEQ;  // row stride SEQ
  const int srow = l >> 3;
  const int scol = ((l & 7) ^ srow) << 3;
  const int sw   = (c & 7) << 4;
  const int pswz = (c & 7) << 3;

  f32x4 ctx[4];
#pragma unroll
  for (int f = 0; f < 4; ++f) ctx[f] = f32x4{0.f, 0.f, 0.f, 0.f};

  float* prbase = out + (size_t)2 * SEQ * 1024 +
                  ((size_t)bh * SEQ + qt * 64 + w * 16 + c) * SEQ;

  STAGE_TILE(Ka, 0, kbase + ((size_t)0 * 64 + w * 16) * 64, 64);
  STAGE_TILE(Va, 0, vbase + (size_t)(w * 16) * SEQ + 0 * 64, SEQ);
  __syncthreads();

  for (int kt = 0; kt < 32; ++kt) {
    const int buf = kt & 1;
    if (kt < 31) {
      STAGE_TILE(Ka, buf ^ 1, kbase + ((size_t)(kt + 1) * 64 + w * 16) * 64, 64);
      STAGE_TILE(Va, buf ^ 1, vbase + (size_t)(w * 16) * SEQ + (kt + 1) * 64, SEQ);
    }

    // ---- QK^T: A = K rows (s*16+c), B = Q
    f32x4 sa[4];
#pragma unroll
    for (int s = 0; s < 4; ++s) {
      const unsigned short* kb = &Ka[buf][(s * 16 + c) * 64];
      bf16x8 k0 = *(const bf16x8*)(kb + (((g * 16) ^ sw) >> 1));
      bf16x8 k1 = *(const bf16x8*)(kb + (((64 + g * 16) ^ sw) >> 1));
      sa[s] = f32x4{0.f, 0.f, 0.f, 0.f};
      sa[s] = MFMA(k0, qf0, sa[s], 0, 0, 0);
      sa[s] = MFMA(k1, qf1, sa[s], 0, 0, 0);
    }

    // ---- exp2 -> probs (normalized, from regs) + unnorm bf16 -> Ps
#pragma unroll
    for (int s = 0; s < 4; ++s) {
      f32x4 pw;
      u16x4 pb;
#pragma unroll
      for (int r = 0; r < 4; ++r) {
        float p = exp2f(sa[s][r]);
        pw[r] = p * inv;
        pb[r] = f2b(p);
      }
      *(f32x4*)(prbase + kt * 64 + s * 16 + g * 4) = pw;
      *(u16x4*)(&Ps[w][c * 64 + ((s * 16 + g * 4) ^ pswz)]) = pb;
    }

    // ---- PV: A = P (same-wave scratch), B = V^T
#pragma unroll
    for (int W = 0; W < 2; ++W) {
      bf16x8 pa = *(const bf16x8*)(&Ps[w][c * 64 + ((W * 32 + g * 8) ^ pswz)]);
#pragma unroll
      for (int f = 0; f < 4; ++f) {
        const unsigned short* vb = &Va[buf][(f * 16 + c) * 64];
        bf16x8 vbf = *(const bf16x8*)(vb + (((W * 64 + g * 16) ^ sw) >> 1));
        ctx[f] = MFMA(pa, vbf, ctx[f], 0, 0, 0);
      }
    }

    __syncthreads();
  }

  // ---- ctx epilogue: lane holds C[q = g*4+r][d = f*16+c]
  const int b = bh >> 4, h = bh & 15;
  float invq[4];
#pragma unroll
  for (int r = 0; r < 4; ++r) invq[r] = __shfl(inv, g * 4 + r);
#pragma unroll
  for (int f = 0; f < 4; ++f)
#pragma unroll
    for (int r = 0; r < 4; ++r) {
      int s = qt * 64 + w * 16 + g * 4 + r;
      out[((size_t)b * SEQ + s) * 1024 + h * 64 + f * 16 + c] = ctx[f][r] * invq[r];
    }
}

extern "C" void kernel_launch(void* const* d_in, const int* in_sizes, int n_in,
                              void* d_out, int out_size, void* d_ws, size_t ws_size,
                              hipStream_t stream) {
  (void)in_sizes; (void)n_in; (void)out_size; (void)ws_size;
  const float* x  = (const float*)d_in[0];
  const float* wq = (const float*)d_in[1];
  const float* bq = (const float*)d_in[2];
  const float* wk = (const float*)d_in[3];
  const float* bk = (const float*)d_in[4];
  const float* wv = (const float*)d_in[5];
  const float* bv = (const float*)d_in[6];

  unsigned short* xw_bf = (unsigned short*)d_ws;            // x_bf + w_bf
  unsigned short* x_bf  = xw_bf;
  unsigned short* w_bf  = xw_bf + 4194304;
  unsigned short* q_ws  = xw_bf + 7340032;                  // [32][2048][64]
  unsigned short* k_ws  = q_ws + 4194304;                   // [32][2048][64]
  unsigned short* vt_ws = k_ws + 4194304;                   // [32][64][2048]
  float* invl_ws = (float*)(xw_bf + 19922944);              // [32][2048]
  float* out = (float*)d_out;

  convert_kernel<<<3584, 256, 0, stream>>>(x, wq, wk, wv, xw_bf);
  gemm_qkv<0><<<dim3(32, 16), 256, 0, stream>>>(x_bf, w_bf, bq, bk, bv, q_ws, k_ws, vt_ws);
  gemm_qkv<1><<<dim3(32, 8), 256, 0, stream>>>(x_bf, w_bf, bq, bk, bv, q_ws, k_ws, vt_ws);
  rowsum_kernel<<<1024, 256, 0, stream>>>(q_ws, k_ws, invl_ws);
  attnpv_kernel<<<1024, 256, 0, stream>>>(q_ws, k_ws, vt_ws, invl_ws, out);
}